// Round 1
// 1258.357 us; speedup vs baseline: 1.3912x; 1.3912x over previous
//
#include <hip/hip_runtime.h>
#include <hip/hip_bf16.h>
#include <math.h>

// Problem constants (B=8,S=4096 -> N=32768 tokens)
#define NTOK   32768
#define HDIM   1024
#define FDIM   2048
#define F4DIM  512
#define NEXP   8
#define CAP    4096
#define EPSV   1e-6f

typedef __bf16 v8bf __attribute__((ext_vector_type(8)));
typedef float  v4f  __attribute__((ext_vector_type(4)));

// fp32 -> bf16 bits, round-to-nearest-even (finite inputs only)
__device__ __forceinline__ unsigned short f2b(float f) {
  unsigned int u = __float_as_uint(f);
  unsigned int r = (u + 0x7FFFu + ((u >> 16) & 1u)) >> 16;
  return (unsigned short)r;
}
__device__ __forceinline__ float b2f(unsigned short u) {
  return __uint_as_float(((unsigned int)u) << 16);
}

// async global->LDS, 16B per lane. LDS dest is WAVE-UNIFORM base + lane*16
// (m104/m108); global src is per-lane (m173) -> swizzle lives in the source addr.
__device__ __forceinline__ void gload16(unsigned short* lds, const unsigned short* g) {
  __builtin_amdgcn_global_load_lds(
      (const __attribute__((address_space(1))) unsigned int*)g,
      (__attribute__((address_space(3))) unsigned int*)lds, 16, 0, 0);
}

// ---------------- weight transpose + bf16 cast ----------------
// in: [z][rows][cols] fp32 row-major  ->  out: [z][cols][rows] bf16
__global__ __launch_bounds__(256) void transpose_cast(
    const float* __restrict__ in, unsigned short* __restrict__ out,
    int rows, int cols)
{
  __shared__ float tile[32][33];
  size_t zo = (size_t)blockIdx.z * rows * cols;
  in  += zo;
  out += zo;
  int c0 = blockIdx.x * 32, r0 = blockIdx.y * 32;
  int tx = threadIdx.x & 31, ty = threadIdx.x >> 5; // ty in 0..7
  for (int i = ty; i < 32; i += 8)
    tile[i][tx] = in[(size_t)(r0 + i) * cols + c0 + tx];
  __syncthreads();
  for (int i = ty; i < 32; i += 8)
    out[(size_t)(c0 + i) * rows + r0 + tx] = f2b(tile[tx][i]);
}

// ---------------- router: logits, softmax, top-2 ----------------
__global__ __launch_bounds__(256) void router_kernel(
    const float* __restrict__ x, const float* __restrict__ Wr,
    int* __restrict__ e1, int* __restrict__ e2,
    float* __restrict__ w1, float* __restrict__ w2)
{
  int wave = threadIdx.x >> 6, lane = threadIdx.x & 63;
  int t = blockIdx.x * 4 + wave;
  const float* xr = x + (size_t)t * HDIM;
  float acc[NEXP];
#pragma unroll
  for (int e = 0; e < NEXP; e++) acc[e] = 0.f;
  for (int j = 0; j < HDIM / 64; j++) {
    int h = lane + 64 * j;
    float v = xr[h];
    const float* wr = Wr + (size_t)h * NEXP;
#pragma unroll
    for (int e = 0; e < NEXP; e++) acc[e] += v * wr[e];
  }
#pragma unroll
  for (int e = 0; e < NEXP; e++) {
    float s = acc[e];
#pragma unroll
    for (int off = 32; off > 0; off >>= 1) s += __shfl_xor(s, off);
    acc[e] = s;
  }
  if (lane == 0) {
    float m = acc[0];
#pragma unroll
    for (int e = 1; e < NEXP; e++) m = fmaxf(m, acc[e]);
    float p[NEXP], sum = 0.f;
#pragma unroll
    for (int e = 0; e < NEXP; e++) { p[e] = expf(acc[e] - m); sum += p[e]; }
    float inv = 1.f / sum;
    // top-1: lowest index on ties (strict >)
    int b1 = 0; float v1 = p[0];
#pragma unroll
    for (int e = 1; e < NEXP; e++) if (p[e] > v1) { v1 = p[e]; b1 = e; }
    int b2 = -1; float v2 = -1.f;
#pragma unroll
    for (int e = 0; e < NEXP; e++) if (e != b1 && p[e] > v2) { v2 = p[e]; b2 = e; }
    e1[t] = b1; e2[t] = b2;
    w1[t] = v1 * inv; w2[t] = v2 * inv;
  }
}

// ---------------- capacity scan (exact cumsum order) ----------------
__global__ __launch_bounds__(256) void scan_count(
    const int* __restrict__ e1, const int* __restrict__ e2, int* __restrict__ chunkCnt)
{
  __shared__ int cnt[NEXP];
  if (threadIdx.x < NEXP) cnt[threadIdx.x] = 0;
  __syncthreads();
  int a = blockIdx.x * 256 + threadIdx.x;     // assignment id, 2N total
  int t = a >> 1;
  int e = (a & 1) ? e2[t] : e1[t];
  atomicAdd(&cnt[e], 1);
  __syncthreads();
  if (threadIdx.x < NEXP) chunkCnt[blockIdx.x * NEXP + threadIdx.x] = cnt[threadIdx.x];
}

__global__ __launch_bounds__(64) void scan_base(
    const int* __restrict__ chunkCnt, int* __restrict__ chunkBase)
{
  int e = threadIdx.x;
  if (e >= NEXP) return;
  int run = 0;
  for (int b = 0; b < 256; b++) {
    chunkBase[b * NEXP + e] = run;
    run += chunkCnt[b * NEXP + e];
  }
}

__global__ __launch_bounds__(64) void scan_pos(
    const int* __restrict__ e1, const int* __restrict__ e2,
    const int* __restrict__ chunkBase,
    int* __restrict__ posArr, int* __restrict__ slotTok)
{
  __shared__ int se[256];
  __shared__ int spos[256];
  int a0 = blockIdx.x * 256;
  for (int i = threadIdx.x; i < 256; i += 64) {
    int a = a0 + i;
    int t = a >> 1;
    se[i] = (a & 1) ? e2[t] : e1[t];
  }
  __syncthreads();
  if (threadIdx.x == 0) {
    int cnt[NEXP];
#pragma unroll
    for (int e = 0; e < NEXP; e++) cnt[e] = chunkBase[blockIdx.x * NEXP + e];
    for (int i = 0; i < 256; i++) spos[i] = cnt[se[i]]++;
  }
  __syncthreads();
  for (int i = threadIdx.x; i < 256; i += 64) {
    int a = a0 + i;
    int p = spos[i];
    posArr[a] = p;
    if (p < CAP) slotTok[se[i] * CAP + p] = a;   // store assignment id
  }
}

__global__ __launch_bounds__(256) void compute_ovf(
    const int* __restrict__ posArr, int* __restrict__ ovf)
{
  int t = blockIdx.x * 256 + threadIdx.x;
  ovf[t] = (posArr[2 * t] >= CAP || posArr[2 * t + 1] >= CAP) ? 1 : 0;
}

// ---------------- build RMSNorm'd bf16 A buffers ----------------
__global__ __launch_bounds__(256) void build_A(
    const float* __restrict__ x, const float* __restrict__ normw,
    const int* __restrict__ slotTok, unsigned short* __restrict__ A)
{
  int wave = threadIdx.x >> 6, lane = threadIdx.x & 63;
  int row = blockIdx.x * 4 + wave;            // [0, NEXP*CAP)
  int e = row >> 12;                          // /CAP
  ushort4* outp = (ushort4*)(A + (size_t)row * HDIM);
  int a = slotTok[row];
  if (a < 0) {
    ushort4 z; z.x = z.y = z.z = z.w = 0;
#pragma unroll
    for (int j = 0; j < 4; j++) outp[lane + 64 * j] = z;
    return;
  }
  int t = a >> 1;
  const float4* xr = (const float4*)(x + (size_t)t * HDIM);
  const float4* nw = (const float4*)(normw + (size_t)e * HDIM);
  float4 v[4];
  float ss = 0.f;
#pragma unroll
  for (int j = 0; j < 4; j++) {
    v[j] = xr[lane + 64 * j];
    ss += v[j].x * v[j].x + v[j].y * v[j].y + v[j].z * v[j].z + v[j].w * v[j].w;
  }
#pragma unroll
  for (int off = 32; off > 0; off >>= 1) ss += __shfl_xor(ss, off);
  float scale = rsqrtf(ss * (1.f / HDIM) + EPSV);
#pragma unroll
  for (int j = 0; j < 4; j++) {
    float4 w = nw[lane + 64 * j];
    ushort4 ov;
    ov.x = f2b(v[j].x * scale * w.x);
    ov.y = f2b(v[j].y * scale * w.y);
    ov.z = f2b(v[j].z * scale * w.z);
    ov.w = f2b(v[j].w * scale * w.w);
    outp[lane + 64 * j] = ov;
  }
}

__global__ __launch_bounds__(256) void build_fA(
    const float* __restrict__ x, const float* __restrict__ fnorm,
    unsigned short* __restrict__ A)
{
  int wave = threadIdx.x >> 6, lane = threadIdx.x & 63;
  int t = blockIdx.x * 4 + wave;
  ushort4* outp = (ushort4*)(A + (size_t)t * HDIM);
  const float4* xr = (const float4*)(x + (size_t)t * HDIM);
  const float4* nw = (const float4*)fnorm;
  float4 v[4];
  float ss = 0.f;
#pragma unroll
  for (int j = 0; j < 4; j++) {
    v[j] = xr[lane + 64 * j];
    ss += v[j].x * v[j].x + v[j].y * v[j].y + v[j].z * v[j].z + v[j].w * v[j].w;
  }
#pragma unroll
  for (int off = 32; off > 0; off >>= 1) ss += __shfl_xor(ss, off);
  float scale = rsqrtf(ss * (1.f / HDIM) + EPSV);
#pragma unroll
  for (int j = 0; j < 4; j++) {
    float4 w = nw[lane + 64 * j];
    ushort4 ov;
    ov.x = f2b(v[j].x * scale * w.x);
    ov.y = f2b(v[j].y * scale * w.y);
    ov.z = f2b(v[j].z * scale * w.z);
    ov.w = f2b(v[j].w * scale * w.w);
    outp[lane + 64 * j] = ov;
  }
}

// ---------------- MFMA GEMM (m97 structure: global_load_lds + linear swizzled LDS) ----------------
// A: [z][M][K] bf16 row-major. B,B2: [z][N][K] bf16 (pre-transposed weights).
// MODE 0: OutB = A@B^T (bf16)
// MODE 1: OutB = gelu_exact(A@B^T) * (A@B2^T) (bf16)
// MODE 2: rows with ovf[row]: OutF[row] = Xres[row] + A@B^T (fp32), else skip
//
// LDS tiles are LINEAR [128][32] bf16 (8KB each; global_load_lds requires
// contiguous dest). Bank-conflict fix is a both-sides 16B-chunk XOR swizzle
// (rule #21): chunk' = chunk ^ ((row>>1)&3), applied identically to the
// per-lane GLOBAL source address (staging) and the ds_read address (frags).
// Both are loop-invariant -> zero per-iteration VALU cost. This spreads the
// 16-lane column read across all 8 LDS bank groups (2 lanes/group = free, m136).
template<int MODE>
__global__ __launch_bounds__(256, 2) void gemm_kernel(
    const unsigned short* __restrict__ A, size_t strideA,
    const unsigned short* __restrict__ B, size_t strideB,
    const unsigned short* __restrict__ B2,
    unsigned short* __restrict__ OutB, size_t strideO,
    float* __restrict__ OutF,
    const float* __restrict__ Xres,
    const int* __restrict__ ovf,
    int M, int N, int K)
{
  __shared__ __align__(16) unsigned short sA[128 * 32];
  __shared__ __align__(16) unsigned short sB[128 * 32];
  __shared__ __align__(16) unsigned short sB2[(MODE == 1) ? 128 * 32 : 16];

  const int tid = threadIdx.x;
  const int wave = tid >> 6, lane = tid & 63;
  const int wm = wave >> 1, wn = wave & 1;
  const int quad = lane >> 4, l16 = lane & 15;

  const int m0 = blockIdx.y * 128;
  const int n0 = blockIdx.x * 128;
  const int z = blockIdx.z;

  const unsigned short* Ab = A + (size_t)z * strideA + (size_t)m0 * K;
  const unsigned short* Bb = B + (size_t)z * strideB + (size_t)n0 * K;
  const unsigned short* B2b = (MODE == 1) ? (B2 + (size_t)z * strideB + (size_t)n0 * K) : nullptr;

  // ---- staging addressing: wave stages rows [wave*32, wave*32+32) of each tile,
  //      2 instructions x 16 rows. lane = lr*4+lc -> (row lr, 16B chunk lc).
  const int r0 = wave * 32;
  const int lr = lane >> 2;                    // 0..15 row within 16-row chunk
  const int lc = lane & 3;                     // 16B chunk within 64B row
  const int cch = (lc ^ ((lr >> 1) & 3)) * 8;  // swizzled source chunk (elements)
  // note: (row>>1)&3 depends only on lr since r0 and r0+16 are multiples of 16.

  const unsigned short* gA0 = Ab + (size_t)(r0 + lr) * K + cch;
  const unsigned short* gA1 = Ab + (size_t)(r0 + 16 + lr) * K + cch;
  const unsigned short* gB0 = Bb + (size_t)(r0 + lr) * K + cch;
  const unsigned short* gB1 = Bb + (size_t)(r0 + 16 + lr) * K + cch;
  const unsigned short* gC0 = (MODE == 1) ? (B2b + (size_t)(r0 + lr) * K + cch) : nullptr;
  const unsigned short* gC1 = (MODE == 1) ? (B2b + (size_t)(r0 + 16 + lr) * K + cch) : nullptr;

  unsigned short* lA0 = &sA[r0 * 32];          // wave-uniform LDS bases
  unsigned short* lA1 = &sA[(r0 + 16) * 32];
  unsigned short* lB0 = &sB[r0 * 32];
  unsigned short* lB1 = &sB[(r0 + 16) * 32];
  unsigned short* lC0 = (MODE == 1) ? &sB2[r0 * 32] : nullptr;
  unsigned short* lC1 = (MODE == 1) ? &sB2[(r0 + 16) * 32] : nullptr;

  // ---- fragment read pointers (loop-invariant, swizzled chunk = quad ^ s(row))
  const int rch = (quad ^ ((l16 >> 1) & 3)) * 8;  // same: (row>>1)&3 == (l16>>1)&3
  const unsigned short* pA = &sA[(wm * 64 + l16) * 32 + rch];
  const unsigned short* pB = &sB[(wn * 64 + l16) * 32 + rch];
  const unsigned short* pC = (MODE == 1) ? &sB2[(wn * 64 + l16) * 32 + rch] : &sB2[0];

  v4f acc[4][4];
  v4f acc2[(MODE == 1) ? 4 : 1][(MODE == 1) ? 4 : 1];
#pragma unroll
  for (int i = 0; i < 4; i++)
#pragma unroll
    for (int j = 0; j < 4; j++) acc[i][j] = (v4f){0.f, 0.f, 0.f, 0.f};
  if constexpr (MODE == 1) {
#pragma unroll
    for (int i = 0; i < 4; i++)
#pragma unroll
      for (int j = 0; j < 4; j++) acc2[i][j] = (v4f){0.f, 0.f, 0.f, 0.f};
  }

  for (int k0 = 0; k0 < K; k0 += 32) {
    // async stage next K-slice (16B/lane, direct to LDS, no VGPR roundtrip)
    gload16(lA0, gA0); gA0 += 32;
    gload16(lA1, gA1); gA1 += 32;
    gload16(lB0, gB0); gB0 += 32;
    gload16(lB1, gB1); gB1 += 32;
    if constexpr (MODE == 1) {
      gload16(lC0, gC0); gC0 += 32;
      gload16(lC1, gC1); gC1 += 32;
    }
    __syncthreads();   // drains vmcnt(0): staged data visible

    v8bf af[4], bfr[4], cfr[4];
#pragma unroll
    for (int i = 0; i < 4; i++) {
      af[i]  = *(const v8bf*)(pA + i * 512);   // +16 rows per fragment
      bfr[i] = *(const v8bf*)(pB + i * 512);
      if constexpr (MODE == 1) cfr[i] = *(const v8bf*)(pC + i * 512);
    }
#pragma unroll
    for (int mi = 0; mi < 4; mi++)
#pragma unroll
      for (int nj = 0; nj < 4; nj++) {
        acc[mi][nj] = __builtin_amdgcn_mfma_f32_16x16x32_bf16(af[mi], bfr[nj], acc[mi][nj], 0, 0, 0);
        if constexpr (MODE == 1)
          acc2[mi][nj] = __builtin_amdgcn_mfma_f32_16x16x32_bf16(af[mi], cfr[nj], acc2[mi][nj], 0, 0, 0);
      }
    __syncthreads();   // frag reads done before next stage overwrites
  }

  // epilogue: C/D layout col=lane&15, row=quad*4+reg
  if constexpr (MODE == 0 || MODE == 1) {
    unsigned short* Ob = OutB + (size_t)z * strideO;
#pragma unroll
    for (int mi = 0; mi < 4; mi++) {
#pragma unroll
      for (int r = 0; r < 4; r++) {
        int row = m0 + wm * 64 + mi * 16 + quad * 4 + r;
#pragma unroll
        for (int nj = 0; nj < 4; nj++) {
          int col = n0 + wn * 64 + nj * 16 + l16;
          float vv;
          if constexpr (MODE == 1) {
            float g = acc[mi][nj][r];
            float u = acc2[mi][nj][r];
            vv = 0.5f * g * (1.0f + erff(g * 0.70710678118654752f)) * u;
          } else {
            vv = acc[mi][nj][r];
          }
          Ob[(size_t)row * N + col] = f2b(vv);
        }
      }
    }
  } else {
#pragma unroll
    for (int mi = 0; mi < 4; mi++) {
#pragma unroll
      for (int r = 0; r < 4; r++) {
        int row = m0 + wm * 64 + mi * 16 + quad * 4 + r;
        if (!ovf[row]) continue;
#pragma unroll
        for (int nj = 0; nj < 4; nj++) {
          int col = n0 + wn * 64 + nj * 16 + l16;
          OutF[(size_t)row * N + col] = Xres[(size_t)row * N + col] + acc[mi][nj][r];
        }
      }
    }
  }
}

// ---------------- combine (non-overflow tokens) ----------------
__global__ __launch_bounds__(256) void combine_kernel(
    const float* __restrict__ x,
    const float* __restrict__ w1, const float* __restrict__ w2,
    const int* __restrict__ e1, const int* __restrict__ e2,
    const int* __restrict__ posArr, const int* __restrict__ ovf,
    const unsigned short* __restrict__ Y, float* __restrict__ out)
{
  int wave = threadIdx.x >> 6, lane = threadIdx.x & 63;
  int t = blockIdx.x * 4 + wave;
  if (ovf[t]) return;   // fallback GEMM wrote this row
  float a1 = w1[t], a2 = w2[t];
  int p1 = posArr[2 * t], p2 = posArr[2 * t + 1];
  const ushort4* y1 = (const ushort4*)(Y + ((size_t)e1[t] * CAP + p1) * HDIM);
  const ushort4* y2 = (const ushort4*)(Y + ((size_t)e2[t] * CAP + p2) * HDIM);
  const float4* xr = (const float4*)(x + (size_t)t * HDIM);
  float4* o = (float4*)(out + (size_t)t * HDIM);
  float base = 1.f + a1 + a2;
#pragma unroll
  for (int j = 0; j < 4; j++) {
    int i = lane + 64 * j;
    float4 xv = xr[i];
    ushort4 u1 = y1[i], u2 = y2[i];
    float4 r;
    r.x = base * xv.x + a1 * b2f(u1.x) + a2 * b2f(u2.x);
    r.y = base * xv.y + a1 * b2f(u1.y) + a2 * b2f(u2.y);
    r.z = base * xv.z + a1 * b2f(u1.z) + a2 * b2f(u2.z);
    r.w = base * xv.w + a1 * b2f(u1.w) + a2 * b2f(u2.w);
    o[i] = r;
  }
}

// ---------------- launch ----------------
extern "C" void kernel_launch(void* const* d_in, const int* in_sizes, int n_in,
                              void* d_out, int out_size, void* d_ws, size_t ws_size,
                              hipStream_t stream) {
  const float* x     = (const float*)d_in[0];
  const float* Wr    = (const float*)d_in[1];
  const float* normw = (const float*)d_in[2];
  const float* Wg    = (const float*)d_in[3];
  const float* Wu    = (const float*)d_in[4];
  const float* Wd    = (const float*)d_in[5];
  const float* fnorm = (const float*)d_in[6];
  const float* fWg   = (const float*)d_in[7];
  const float* fWu   = (const float*)d_in[8];
  const float* fWd   = (const float*)d_in[9];
  float* out = (float*)d_out;

  // workspace layout (~356 MiB); fA aliases A, fP aliases P
  char* p = (char*)d_ws;
  auto alloc = [&](size_t bytes) {
    char* r = p; p += (bytes + 255) & ~(size_t)255; return r;
  };
  unsigned short* WgT  = (unsigned short*)alloc((size_t)NEXP * FDIM * HDIM * 2);
  unsigned short* WuT  = (unsigned short*)alloc((size_t)NEXP * FDIM * HDIM * 2);
  unsigned short* WdT  = (unsigned short*)alloc((size_t)NEXP * HDIM * FDIM * 2);
  unsigned short* fWgT = (unsigned short*)alloc((size_t)F4DIM * HDIM * 2);
  unsigned short* fWuT = (unsigned short*)alloc((size_t)F4DIM * HDIM * 2);
  unsigned short* fWdT = (unsigned short*)alloc((size_t)HDIM * F4DIM * 2);
  unsigned short* Abuf = (unsigned short*)alloc((size_t)NEXP * CAP * HDIM * 2);   // later fA
  unsigned short* Pbuf = (unsigned short*)alloc((size_t)NEXP * CAP * FDIM * 2);   // later fP
  unsigned short* Ybuf = (unsigned short*)alloc((size_t)NEXP * CAP * HDIM * 2);
  int*   e1      = (int*)alloc((size_t)NTOK * 4);
  int*   e2      = (int*)alloc((size_t)NTOK * 4);
  float* w1      = (float*)alloc((size_t)NTOK * 4);
  float* w2      = (float*)alloc((size_t)NTOK * 4);
  int*   posArr  = (int*)alloc((size_t)2 * NTOK * 4);
  int*   ovf     = (int*)alloc((size_t)NTOK * 4);
  int*   chunkCnt  = (int*)alloc(256 * NEXP * 4);
  int*   chunkBase = (int*)alloc(256 * NEXP * 4);
  int*   slotTok   = (int*)alloc((size_t)NEXP * CAP * 4);
  unsigned short* fAbuf = Abuf;   // alias: A dead after GEMM1
  unsigned short* fPbuf = Pbuf;   // alias: P dead after GEMM2

  hipMemsetAsync(slotTok, 0xFF, (size_t)NEXP * CAP * 4, stream);  // -1

  // weight transpose+cast to bf16 [N][K]
  transpose_cast<<<dim3(FDIM / 32, HDIM / 32, NEXP), 256, 0, stream>>>(Wg, WgT, HDIM, FDIM);
  transpose_cast<<<dim3(FDIM / 32, HDIM / 32, NEXP), 256, 0, stream>>>(Wu, WuT, HDIM, FDIM);
  transpose_cast<<<dim3(HDIM / 32, FDIM / 32, NEXP), 256, 0, stream>>>(Wd, WdT, FDIM, HDIM);
  transpose_cast<<<dim3(F4DIM / 32, HDIM / 32, 1), 256, 0, stream>>>(fWg, fWgT, HDIM, F4DIM);
  transpose_cast<<<dim3(F4DIM / 32, HDIM / 32, 1), 256, 0, stream>>>(fWu, fWuT, HDIM, F4DIM);
  transpose_cast<<<dim3(HDIM / 32, F4DIM / 32, 1), 256, 0, stream>>>(fWd, fWdT, F4DIM, HDIM);

  router_kernel<<<NTOK / 4, 256, 0, stream>>>(x, Wr, e1, e2, w1, w2);
  scan_count<<<256, 256, 0, stream>>>(e1, e2, chunkCnt);
  scan_base<<<1, 64, 0, stream>>>(chunkCnt, chunkBase);
  scan_pos<<<256, 64, 0, stream>>>(e1, e2, chunkBase, posArr, slotTok);
  compute_ovf<<<NTOK / 256, 256, 0, stream>>>(posArr, ovf);

  build_A<<<NEXP * CAP / 4, 256, 0, stream>>>(x, normw, slotTok, Abuf);

  // expert GLU: P = gelu(A@Wg) * (A@Wu)
  gemm_kernel<1><<<dim3(FDIM / 128, CAP / 128, NEXP), 256, 0, stream>>>(
      Abuf, (size_t)CAP * HDIM, WgT, (size_t)FDIM * HDIM, WuT,
      Pbuf, (size_t)CAP * FDIM, nullptr, nullptr, nullptr, CAP, FDIM, HDIM);
  // Y = P@Wd
  gemm_kernel<0><<<dim3(HDIM / 128, CAP / 128, NEXP), 256, 0, stream>>>(
      Pbuf, (size_t)CAP * FDIM, WdT, (size_t)HDIM * FDIM, nullptr,
      Ybuf, (size_t)CAP * HDIM, nullptr, nullptr, nullptr, CAP, HDIM, FDIM);

  // fallback path (A region and P region reused)
  build_fA<<<NTOK / 4, 256, 0, stream>>>(x, fnorm, fAbuf);
  gemm_kernel<1><<<dim3(F4DIM / 128, NTOK / 128, 1), 256, 0, stream>>>(
      fAbuf, 0, fWgT, 0, fWuT,
      fPbuf, 0, nullptr, nullptr, nullptr, NTOK, F4DIM, HDIM);
  gemm_kernel<2><<<dim3(HDIM / 128, NTOK / 128, 1), 256, 0, stream>>>(
      fPbuf, 0, fWdT, 0, nullptr,
      nullptr, 0, out, x, ovf, NTOK, HDIM, F4DIM);

  combine_kernel<<<NTOK / 4, 256, 0, stream>>>(x, w1, w2, e1, e2, posArr, ovf, Ybuf, out);
}